// Round 5
// baseline (54588.879 us; speedup 1.0000x reference)
//
#include <hip/hip_runtime.h>
#include <stdint.h>

#define T_STEPS 8192
#define K_TAGS 1024
#define D_DIM 1024
#define START_TAG 1022
#define STOP_TAG 1023
#define NEGV (-10000.0f)
#define LOG2E 1.4426950408889634f
#define LN2 0.6931471805599453f

#define NBLK 1024            // one single-wave block per row
#define TAG(u) ((unsigned)((u) >> 32))

// ---- agent-scope (device) 64-bit payload+tag atomics -----------------------
static __device__ __forceinline__ unsigned long long ld_agent_u64(
    const unsigned long long* p) {
  return __hip_atomic_load(p, __ATOMIC_RELAXED, __HIP_MEMORY_SCOPE_AGENT);
}
static __device__ __forceinline__ void st_agent_u64(unsigned long long* p,
                                                    unsigned long long v) {
  __hip_atomic_store(p, v, __ATOMIC_RELAXED, __HIP_MEMORY_SCOPE_AGENT);
}

// ---- wave64 DPP reductions (VALU-only, no DS ops) --------------------------
// row_shr:1/2/4/8 then row_bcast:15, row_bcast:31 -> total lands in lane 63.
template <int CTRL>
static __device__ __forceinline__ float dpp_mov(float x, float old) {
  return __int_as_float(__builtin_amdgcn_update_dpp(
      __float_as_int(old), __float_as_int(x), CTRL, 0xF, 0xF, false));
}
static __device__ __forceinline__ float wave_red_max63(float x) {
  const float NI = -3.0e38f;
  x = fmaxf(x, dpp_mov<0x111>(x, NI));
  x = fmaxf(x, dpp_mov<0x112>(x, NI));
  x = fmaxf(x, dpp_mov<0x114>(x, NI));
  x = fmaxf(x, dpp_mov<0x118>(x, NI));
  x = fmaxf(x, dpp_mov<0x142>(x, NI));   // row_bcast:15
  x = fmaxf(x, dpp_mov<0x143>(x, NI));   // row_bcast:31
  return x;                               // lane 63 holds wave max
}
static __device__ __forceinline__ float wave_red_sum63(float x) {
  x += dpp_mov<0x111>(x, 0.0f);
  x += dpp_mov<0x112>(x, 0.0f);
  x += dpp_mov<0x114>(x, 0.0f);
  x += dpp_mov<0x118>(x, 0.0f);
  x += dpp_mov<0x142>(x, 0.0f);
  x += dpp_mov<0x143>(x, 0.0f);
  return x;                               // lane 63 holds wave sum
}

// ---- workspace init (runs every call; ws is NOT re-poisoned between replays)
__global__ void init_ws_kernel(unsigned long long* fvbuf) {
  int i = blockIdx.x * blockDim.x + threadIdx.x;
  if (i < 2 * K_TAGS) fvbuf[i] = 0ull;  // tag 0 everywhere
}

// ---- gates: one wave per step t; t==T_STEPS computes the terminal gate -----
__global__ __launch_bounds__(256) void gate_kernel(
    const float* __restrict__ reps, const float* __restrict__ wc,
    const float* __restrict__ wu, const int* __restrict__ spk,
    float* __restrict__ gate, float* __restrict__ g_term) {
  const int gw = (int)((blockIdx.x * blockDim.x + threadIdx.x) >> 6);
  const int lane = threadIdx.x & 63;
  if (gw > T_STEPS) return;
  const int tcur = (gw < T_STEPS) ? gw : (T_STEPS - 1);
  const int tprv = (gw < T_STEPS) ? (gw > 0 ? gw - 1 : 0) : (T_STEPS - 1);
  const float* cur = reps + (size_t)tcur * D_DIM;
  const float* prv = reps + (size_t)tprv * D_DIM;
  float sc = 0.f, su = 0.f;
#pragma unroll
  for (int c = 0; c < 4; ++c) {
    const int d = lane * 4 + c * 256;
    float4 rp = *(const float4*)(prv + d);
    float4 rc = *(const float4*)(cur + d);
    float4 w1 = *(const float4*)(wc + d);
    float4 w2 = *(const float4*)(wc + D_DIM + d);
    float4 w3 = *(const float4*)(wu + d);
    float4 w4 = *(const float4*)(wu + D_DIM + d);
    sc += rp.x * w1.x + rp.y * w1.y + rp.z * w1.z + rp.w * w1.w;
    sc += rc.x * w2.x + rc.y * w2.y + rc.z * w2.z + rc.w * w2.w;
    su += rp.x * w3.x + rp.y * w3.y + rp.z * w3.z + rp.w * w3.w;
    su += rc.x * w4.x + rc.y * w4.y + rc.z * w4.z + rc.w * w4.w;
  }
#pragma unroll
  for (int off = 32; off; off >>= 1) {
    sc += __shfl_xor(sc, off);
    su += __shfl_xor(su, off);
  }
  if (lane == 0) {
    if (gw < T_STEPS) {
      bool uc = (gw > 0) && (spk[gw] != 0);
      float x = uc ? sc : su;
      gate[gw] = 1.0f / (1.0f + __expf(-x));
    } else {
      *g_term = 1.0f / (1.0f + __expf(-su));
    }
  }
}

// ---- persistent CRF forward scan: independent-wave swarm -------------------
// 1024 blocks x 64 threads; block r owns output row r. Lane l holds matrix
// cells (r, p) and state entries p = l + 64c, c=0..15 (coalesced stride-64).
// Per step: poll 16 tagged u64 -> in-reg max (DPP) -> 16 exp2 cells -> DPP
// sum -> lane63 publishes. No barriers, no LDS, no cross-wave coupling.
__global__ __launch_bounds__(64) void crf_kernel(
    const float* __restrict__ feats, const float* __restrict__ ti,
    const float* __restrict__ ta, const float* __restrict__ gate,
    const float* __restrict__ g_term_p, unsigned long long* fvb,
    float* __restrict__ out) {
  const int r = blockIdx.x;
  const int lane = threadIdx.x;

  // register-resident, log2-scaled matrix slice for row r
  float ta2[16], df2[16];
  {
    const float* taR = ta + (size_t)r * K_TAGS + lane;
    const float* tiR = ti + (size_t)r * K_TAGS + lane;
#pragma unroll
    for (int c = 0; c < 16; ++c) {
      float a = taR[64 * c];
      float i_ = tiR[64 * c];
      ta2[c] = a * LOG2E;
      df2[c] = (i_ - a) * LOG2E;
    }
  }

  // publish initial state s_0 (tag 1) for our row into slot 0
  if (lane == 0) {
    float v = (r == START_TAG) ? 0.0f : NEGV * LOG2E;
    st_agent_u64(&fvb[r],
                 (1ull << 32) | (unsigned long long)__float_as_uint(v));
  }

  float featv = (lane == 63) ? feats[r] : 0.0f;  // feats[0][r]

  for (int t = 0; t < T_STEPS; ++t) {
    const int slot = t & 1;
    const unsigned want = (unsigned)(t + 1);
    const float g = gate[t];  // uniform: s_load, overlaps the poll

    // 1) poll all 1024 entries (16 stride-64 u64 per lane)
    unsigned long long* ep = &fvb[slot * K_TAGS + lane];
    unsigned long long u[16];
    for (;;) {
      unsigned bad = 0;
#pragma unroll
      for (int c = 0; c < 16; ++c) u[c] = ld_agent_u64(ep + 64 * c);
#pragma unroll
      for (int c = 0; c < 16; ++c) bad |= (unsigned)(TAG(u[c]) < want);
      if (!__any((int)bad)) break;
    }

    // prefetch next step's emission; latency hides under this whole step
    float featv_next = 0.0f;
    if (lane == 63 && t + 1 < T_STEPS)
      featv_next = feats[(size_t)(t + 1) * K_TAGS + r];

    float fv[16];
#pragma unroll
    for (int c = 0; c < 16; ++c) fv[c] = __uint_as_float((unsigned)u[c]);

    // 2) exact shift = max_p fv[p] (bounds exponents in [-134, +8]; safe)
    float m = fv[0];
#pragma unroll
    for (int c = 1; c < 16; ++c) m = fmaxf(m, fv[c]);
    m = wave_red_max63(m);
    const float sh =
        __int_as_float(__builtin_amdgcn_readlane(__float_as_int(m), 63));

    // 3) 16 cells/lane: acc += 2^(ta2 + g*df2 + fv - sh)
    float a0 = 0.f, a1 = 0.f, a2 = 0.f, a3 = 0.f;
#pragma unroll
    for (int c = 0; c < 16; c += 4) {
      a0 += exp2f(__builtin_fmaf(g, df2[c + 0], ta2[c + 0]) + (fv[c + 0] - sh));
      a1 += exp2f(__builtin_fmaf(g, df2[c + 1], ta2[c + 1]) + (fv[c + 1] - sh));
      a2 += exp2f(__builtin_fmaf(g, df2[c + 2], ta2[c + 2]) + (fv[c + 2] - sh));
      a3 += exp2f(__builtin_fmaf(g, df2[c + 3], ta2[c + 3]) + (fv[c + 3] - sh));
    }
    float acc = wave_red_sum63((a0 + a1) + (a2 + a3));

    // 4) lane63 finalizes + publishes (tag t+2) into the other slot.
    //    acc==0 -> -inf (START row): correct and harmless downstream.
    if (lane == 63) {
      float fvnew = sh + __log2f(acc) + featv * LOG2E;
      st_agent_u64(&fvb[(slot ^ 1) * K_TAGS + r],
                   ((unsigned long long)(unsigned)(t + 2) << 32) |
                       (unsigned long long)__float_as_uint(fvnew));
    }
    featv = featv_next;
  }

  // ---- terminal LSE by block STOP_TAG (its ta2/df2 IS the STOP row) --------
  if (r == STOP_TAG) {
    const unsigned want = (unsigned)(T_STEPS + 1);
    unsigned long long* ep = &fvb[(T_STEPS & 1) * K_TAGS + lane];
    unsigned long long u[16];
    for (;;) {
      unsigned bad = 0;
#pragma unroll
      for (int c = 0; c < 16; ++c) u[c] = ld_agent_u64(ep + 64 * c);
#pragma unroll
      for (int c = 0; c < 16; ++c) bad |= (unsigned)(TAG(u[c]) < want);
      if (!__any((int)bad)) break;
    }
    const float gt = *g_term_p;
    float v[16];
#pragma unroll
    for (int c = 0; c < 16; ++c)
      v[c] = __uint_as_float((unsigned)u[c]) +
             __builtin_fmaf(gt, df2[c], ta2[c]);
    float m = v[0];
#pragma unroll
    for (int c = 1; c < 16; ++c) m = fmaxf(m, v[c]);
    m = wave_red_max63(m);
    const float M =
        __int_as_float(__builtin_amdgcn_readlane(__float_as_int(m), 63));
    float e = 0.f;
#pragma unroll
    for (int c = 0; c < 16; ++c) e += exp2f(v[c] - M);
    e = wave_red_sum63(e);
    if (lane == 63) out[0] = (M + __log2f(e)) * LN2;
  }
}

extern "C" void kernel_launch(void* const* d_in, const int* in_sizes, int n_in,
                              void* d_out, int out_size, void* d_ws, size_t ws_size,
                              hipStream_t stream) {
  (void)in_sizes; (void)n_in; (void)out_size; (void)ws_size;
  const float* feats = (const float*)d_in[0];
  const float* reps  = (const float*)d_in[1];
  const float* wc    = (const float*)d_in[2];
  const float* wu    = (const float*)d_in[3];
  const float* ti    = (const float*)d_in[4];
  const float* ta    = (const float*)d_in[5];
  const int*   spk   = (const int*)d_in[6];
  float* out = (float*)d_out;

  // ws layout: fvbuf[2][1024] u64 (16 KiB) | gate[8192] f32 | g_term f32
  unsigned long long* fvbuf = (unsigned long long*)d_ws;
  float* gate  = (float*)((char*)d_ws + 2 * K_TAGS * sizeof(unsigned long long));
  float* gterm = gate + T_STEPS;

  init_ws_kernel<<<dim3(8), dim3(256), 0, stream>>>(fvbuf);
  gate_kernel<<<dim3((T_STEPS + 1 + 3) / 4), dim3(256), 0, stream>>>(
      reps, wc, wu, spk, gate, gterm);
  crf_kernel<<<dim3(NBLK), dim3(64), 0, stream>>>(feats, ti, ta, gate, gterm,
                                                  fvbuf, out);
}

// Round 6
// 24737.381 us; speedup vs baseline: 2.2067x; 2.2067x over previous
//
#include <hip/hip_runtime.h>
#include <stdint.h>

#define T_STEPS 8192
#define K_TAGS 1024
#define D_DIM 1024
#define START_TAG 1022
#define STOP_TAG 1023
#define NEGV (-10000.0f)
#define LOG2E 1.4426950408889634f
#define LN2 0.6931471805599453f
#define MARGIN2 40.0f   // lagged-shift slack (log2 units); r4-proven exact

#define NBLK 64       // blocks in persistent CRF kernel (fewer pollers!)
#define ROWS_PB 16    // K_TAGS / NBLK rows per block; one HALF-WAVE per row
#define TAG(u) ((unsigned)((u) >> 32))

// ---- agent-scope (device) 64-bit payload+tag atomics -----------------------
static __device__ __forceinline__ unsigned long long ld_agent_u64(
    const unsigned long long* p) {
  return __hip_atomic_load(p, __ATOMIC_RELAXED, __HIP_MEMORY_SCOPE_AGENT);
}
static __device__ __forceinline__ void st_agent_u64(unsigned long long* p,
                                                    unsigned long long v) {
  __hip_atomic_store(p, v, __ATOMIC_RELAXED, __HIP_MEMORY_SCOPE_AGENT);
}

// ---- wave64 DPP reductions (VALU-only) -------------------------------------
template <int CTRL>
static __device__ __forceinline__ float dpp_mov(float x, float old) {
  return __int_as_float(__builtin_amdgcn_update_dpp(
      __float_as_int(old), __float_as_int(x), CTRL, 0xF, 0xF, false));
}
// sum over each 32-lane half -> lanes 31 and 63 hold their half's total
static __device__ __forceinline__ float half_red_sum(float x) {
  x += dpp_mov<0x111>(x, 0.0f);   // row_shr:1
  x += dpp_mov<0x112>(x, 0.0f);   // row_shr:2
  x += dpp_mov<0x114>(x, 0.0f);   // row_shr:4
  x += dpp_mov<0x118>(x, 0.0f);   // row_shr:8
  x += dpp_mov<0x142>(x, 0.0f);   // row_bcast:15
  return x;
}
// full 64-lane max -> lane 63
static __device__ __forceinline__ float wave_red_max63(float x) {
  const float NI = -3.0e38f;
  x = fmaxf(x, dpp_mov<0x111>(x, NI));
  x = fmaxf(x, dpp_mov<0x112>(x, NI));
  x = fmaxf(x, dpp_mov<0x114>(x, NI));
  x = fmaxf(x, dpp_mov<0x118>(x, NI));
  x = fmaxf(x, dpp_mov<0x142>(x, NI));
  x = fmaxf(x, dpp_mov<0x143>(x, NI));  // row_bcast:31
  return x;
}
// full 64-lane sum -> lane 63
static __device__ __forceinline__ float wave_red_sum63(float x) {
  x += dpp_mov<0x111>(x, 0.0f);
  x += dpp_mov<0x112>(x, 0.0f);
  x += dpp_mov<0x114>(x, 0.0f);
  x += dpp_mov<0x118>(x, 0.0f);
  x += dpp_mov<0x142>(x, 0.0f);
  x += dpp_mov<0x143>(x, 0.0f);
  return x;
}

// ---- workspace init (runs every call; ws is NOT re-poisoned between replays)
__global__ void init_ws_kernel(unsigned long long* fvbuf, int* bmax) {
  int i = blockIdx.x * blockDim.x + threadIdx.x;
  if (i < 2 * K_TAGS) fvbuf[i] = 0ull;  // tag 0 everywhere
  if (i == 0) *bmax = 0;                // float 0.0 bits; true max is positive
}

// ---- gates: one wave per step t; t==T_STEPS computes the terminal gate -----
__global__ __launch_bounds__(256) void gate_kernel(
    const float* __restrict__ reps, const float* __restrict__ wc,
    const float* __restrict__ wu, const int* __restrict__ spk,
    float* __restrict__ gate, float* __restrict__ g_term) {
  const int gw = (int)((blockIdx.x * blockDim.x + threadIdx.x) >> 6);
  const int lane = threadIdx.x & 63;
  if (gw > T_STEPS) return;
  const int tcur = (gw < T_STEPS) ? gw : (T_STEPS - 1);
  const int tprv = (gw < T_STEPS) ? (gw > 0 ? gw - 1 : 0) : (T_STEPS - 1);
  const float* cur = reps + (size_t)tcur * D_DIM;
  const float* prv = reps + (size_t)tprv * D_DIM;
  float sc = 0.f, su = 0.f;
#pragma unroll
  for (int c = 0; c < 4; ++c) {
    const int d = lane * 4 + c * 256;
    float4 rp = *(const float4*)(prv + d);
    float4 rc = *(const float4*)(cur + d);
    float4 w1 = *(const float4*)(wc + d);
    float4 w2 = *(const float4*)(wc + D_DIM + d);
    float4 w3 = *(const float4*)(wu + d);
    float4 w4 = *(const float4*)(wu + D_DIM + d);
    sc += rp.x * w1.x + rp.y * w1.y + rp.z * w1.z + rp.w * w1.w;
    sc += rc.x * w2.x + rc.y * w2.y + rc.z * w2.z + rc.w * w2.w;
    su += rp.x * w3.x + rp.y * w3.y + rp.z * w3.z + rp.w * w3.w;
    su += rc.x * w4.x + rc.y * w4.y + rc.z * w4.z + rc.w * w4.w;
  }
#pragma unroll
  for (int off = 32; off; off >>= 1) {
    sc += __shfl_xor(sc, off);
    su += __shfl_xor(su, off);
  }
  if (lane == 0) {
    if (gw < T_STEPS) {
      bool uc = (gw > 0) && (spk[gw] != 0);
      float x = uc ? sc : su;
      gate[gw] = 1.0f / (1.0f + __expf(-x));
    } else {
      *g_term = 1.0f / (1.0f + __expf(-su));
    }
  }
}

// ---- global max over elementwise max(ti, ta) (for the lagged LSE shift) ----
__global__ __launch_bounds__(256) void bmax_kernel(
    const float* __restrict__ ti, const float* __restrict__ ta, int* bmax) {
  size_t i = (size_t)blockIdx.x * blockDim.x + threadIdx.x;
  size_t n = (size_t)K_TAGS * K_TAGS;
  float m = 0.f;  // clamped at 0 so int-compare atomicMax is valid
  for (size_t j = i; j < n; j += (size_t)gridDim.x * blockDim.x)
    m = fmaxf(m, fmaxf(ti[j], ta[j]));
#pragma unroll
  for (int off = 32; off; off >>= 1) m = fmaxf(m, __shfl_xor(m, off));
  if ((threadIdx.x & 63) == 0) atomicMax(bmax, __float_as_int(m));
}

// ---- persistent CRF forward scan -------------------------------------------
// 64 blocks x 512 threads (8 waves). Half-wave (32 lanes) owns one row:
// r = 16b + 2w + h. Team lane j owns prevs {2j+64c, 2j+64c+1}, c=0..15.
// Per step: poll 2 contiguous u64/thread -> LDS (float2) -> 1 barrier ->
// lagged shift -> 32 exp2 cells -> DPP half-sum to lanes 31/63 -> publish.
// EA poll footprint: 64 x 8KB = 512KB/round (vs r2's 2MB, r5's 8MB).
__global__ __launch_bounds__(512) void crf_kernel(
    const float* __restrict__ feats, const float* __restrict__ ti,
    const float* __restrict__ ta, const float* __restrict__ gate,
    const float* __restrict__ g_term_p, const int* __restrict__ bmax_p,
    unsigned long long* fvb, float* __restrict__ out) {
  const int b = blockIdx.x;
  const int tid = threadIdx.x;
  const int lane = tid & 63;
  const int w = tid >> 6;              // wave id
  const int j = lane & 31;             // team lane
  const int h = lane >> 5;             // which half-wave (row parity)
  const int r = b * ROWS_PB + w * 2 + h;  // this half-wave's row
  const bool leader = (j == 31);       // lanes 31 and 63
  const int e0 = tid * 2;              // two polled entries per thread

  __shared__ __align__(16) float2 fvs2[2][K_TAGS / 2];
  __shared__ __align__(16) float wredM[2][8];  // slot-buffered lagged blockmax
  __shared__ float wredS[8];

  // register-resident, log2-scaled matrix slice: 32 cells for row r
  float ta2[32], df2[32];
  {
    const float2* taP = reinterpret_cast<const float2*>(ta + (size_t)r * K_TAGS) + j;
    const float2* tiP = reinterpret_cast<const float2*>(ti + (size_t)r * K_TAGS) + j;
#pragma unroll
    for (int c = 0; c < 16; ++c) {
      float2 a = taP[32 * c];
      float2 i_ = tiP[32 * c];
      ta2[2 * c] = a.x * LOG2E;
      df2[2 * c] = (i_.x - a.x) * LOG2E;
      ta2[2 * c + 1] = a.y * LOG2E;
      df2[2 * c + 1] = (i_.y - a.y) * LOG2E;
    }
  }
  const float bmax2 = __int_as_float(*bmax_p) * LOG2E;

  // init lagged-max buffers: max(fv_0) = 0 (START row), used at t=0
  if (tid < 16) wredM[tid >> 3][tid & 7] = 0.0f;

  // publish initial state s_0 (tag 1) into slot 0
  if (tid < ROWS_PB) {
    int rr = b * ROWS_PB + tid;
    float v = (rr == START_TAG) ? 0.0f : NEGV * LOG2E;
    st_agent_u64(&fvb[rr],
                 (1ull << 32) | (unsigned long long)__float_as_uint(v));
  }

  float featv = leader ? feats[r] : 0.0f;  // feats[0][r]

  for (int t = 0; t < T_STEPS; ++t) {
    const int slot = t & 1;
    const unsigned want = (unsigned)(t + 1);
    const float g = gate[t];  // uniform; overlaps the poll

    // 1) poll own 2 contiguous tagged atoms (single vmcnt round)
    unsigned long long* ep = &fvb[slot * K_TAGS + e0];
    unsigned long long u0 = ld_agent_u64(ep + 0);
    unsigned long long u1 = ld_agent_u64(ep + 1);
    while (TAG(u0) < want || TAG(u1) < want) {
      u0 = ld_agent_u64(ep + 0);
      u1 = ld_agent_u64(ep + 1);
    }
    const float v0 = __uint_as_float((unsigned)u0);
    const float v1 = __uint_as_float((unsigned)u1);

    // 2) stash -> one barrier
    fvs2[slot][tid] = make_float2(v0, v1);
    __syncthreads();

    // prefetch next step's emission; latency hides under compute
    float featv_next = 0.0f;
    if (leader && t + 1 < T_STEPS)
      featv_next = feats[(size_t)(t + 1) * K_TAGS + r];

    // 3) lagged shift: blockmax(fv_{t-1}) + bmax2 + margin (exact, r4-proven)
    const float4 mA = *reinterpret_cast<const float4*>(&wredM[slot ^ 1][0]);
    const float4 mB = *reinterpret_cast<const float4*>(&wredM[slot ^ 1][4]);
    const float sh = fmaxf(fmaxf(fmaxf(mA.x, mA.y), fmaxf(mA.z, mA.w)),
                           fmaxf(fmaxf(mB.x, mB.y), fmaxf(mB.z, mB.w))) +
                     bmax2 + MARGIN2;

    // 4) 32 cells: acc += 2^(ta2 + g*df2 + fv - sh); half-waves broadcast-read
    float a0 = 0.f, a1 = 0.f;
    const float2* fp = &fvs2[slot][0] + j;
#pragma unroll
    for (int c = 0; c < 16; ++c) {
      float2 f = fp[32 * c];
      a0 += exp2f(__builtin_fmaf(g, df2[2 * c], ta2[2 * c]) + (f.x - sh));
      a1 += exp2f(__builtin_fmaf(g, df2[2 * c + 1], ta2[2 * c + 1]) + (f.y - sh));
    }
    float acc = half_red_sum(a0 + a1);  // lanes 31/63 hold row sums

    // 5) leaders finalize + publish (tag t+2) into the other slot
    if (leader) {
      float fvnew = sh + __log2f(acc) + featv * LOG2E;  // -inf if acc==0: OK
      st_agent_u64(&fvb[(slot ^ 1) * K_TAGS + r],
                   ((unsigned long long)(unsigned)(t + 2) << 32) |
                       (unsigned long long)__float_as_uint(fvnew));
    }

    // 6) OFF critical path: wave max of polled fv_t -> wredM[slot] for t+1.
    //    Race-free via barrier + tag-chain ordering (r4 argument).
    float lm = wave_red_max63(fmaxf(v0, v1));
    if (lane == 63) wredM[slot][w] = lm;

    featv = featv_next;
  }

  // ---- terminal LSE by the block owning the STOP row -------------------------
  if (b == STOP_TAG / ROWS_PB) {
    const unsigned want = (unsigned)(T_STEPS + 1);
    unsigned long long* ep = &fvb[(T_STEPS & 1) * K_TAGS + e0];
    unsigned long long u0 = ld_agent_u64(ep + 0);
    unsigned long long u1 = ld_agent_u64(ep + 1);
    while (TAG(u0) < want || TAG(u1) < want) {
      u0 = ld_agent_u64(ep + 0);
      u1 = ld_agent_u64(ep + 1);
    }
    const float gt = *g_term_p;
    const float2 tis = *(const float2*)(ti + (size_t)STOP_TAG * K_TAGS + e0);
    const float2 tas = *(const float2*)(ta + (size_t)STOP_TAG * K_TAGS + e0);
    float t0 = __uint_as_float((unsigned)u0) +
               (tas.x + gt * (tis.x - tas.x)) * LOG2E;
    float t1 = __uint_as_float((unsigned)u1) +
               (tas.y + gt * (tis.y - tas.y)) * LOG2E;

    float m = wave_red_max63(fmaxf(t0, t1));
    if (lane == 63) wredM[0][w] = m;
    __syncthreads();
    float mm = wredM[0][0];
#pragma unroll
    for (int i = 1; i < 8; ++i) mm = fmaxf(mm, wredM[0][i]);
    float e = exp2f(t0 - mm) + exp2f(t1 - mm);
    e = wave_red_sum63(e);
    if (lane == 63) wredS[w] = e;
    __syncthreads();
    if (tid == 0) {
      float s = 0.f;
#pragma unroll
      for (int i = 0; i < 8; ++i) s += wredS[i];
      out[0] = (mm + __log2f(s)) * LN2;
    }
  }
}

extern "C" void kernel_launch(void* const* d_in, const int* in_sizes, int n_in,
                              void* d_out, int out_size, void* d_ws, size_t ws_size,
                              hipStream_t stream) {
  (void)in_sizes; (void)n_in; (void)out_size; (void)ws_size;
  const float* feats = (const float*)d_in[0];
  const float* reps  = (const float*)d_in[1];
  const float* wc    = (const float*)d_in[2];
  const float* wu    = (const float*)d_in[3];
  const float* ti    = (const float*)d_in[4];
  const float* ta    = (const float*)d_in[5];
  const int*   spk   = (const int*)d_in[6];
  float* out = (float*)d_out;

  // ws layout: fvbuf[2][1024] u64 (16 KiB) | gate[8192] f32 | g_term f32 | bmax i32
  unsigned long long* fvbuf = (unsigned long long*)d_ws;
  float* gate  = (float*)((char*)d_ws + 2 * K_TAGS * sizeof(unsigned long long));
  float* gterm = gate + T_STEPS;
  int*   bmax  = (int*)(gterm + 1);

  init_ws_kernel<<<dim3(8), dim3(256), 0, stream>>>(fvbuf, bmax);
  gate_kernel<<<dim3((T_STEPS + 1 + 3) / 4), dim3(256), 0, stream>>>(
      reps, wc, wu, spk, gate, gterm);
  bmax_kernel<<<dim3(512), dim3(256), 0, stream>>>(ti, ta, bmax);
  crf_kernel<<<dim3(NBLK), dim3(512), 0, stream>>>(feats, ti, ta, gate, gterm,
                                                   bmax, fvbuf, out);
}